// Round 17
// baseline (66.380 us; speedup 1.0000x reference)
//
#include <hip/hip_runtime.h>
#include <hip/hip_bf16.h>
#include <cstdint>
#include <cstddef>

#define B_ROWS 8192
#define KDIM   4096
#define IN_DIM 2048
#define HIDDEN 2048
#define NJ     32           // 4 gates x 8 wires
#define KC     2            // K-split across blocks (kc=0 -> x, kc=1 -> hx)
#define CHUNK  (KDIM / KC)  // 2048 (exactly the x | hx boundary)
#define BK     64           // k-subtile per pipeline stage
#define SUBT   (CHUNK / BK) // 32
#define MROWS  16           // rows per block (ONE wave)
#define TPB1   64           // 1 wave -> no s_barrier anywhere in the K-loop
#define NBUF   3            // depth-2 prefetch (single-wave: distance-2 mod 3 safe)

typedef __bf16 bf16x8 __attribute__((ext_vector_type(8)));
typedef float  f32x4  __attribute__((ext_vector_type(4)));

__device__ __forceinline__ bf16x8 cvt8(f32x4 a, f32x4 b) {
    bf16x8 r;
    r[0] = (__bf16)a.x; r[1] = (__bf16)a.y; r[2] = (__bf16)a.z; r[3] = (__bf16)a.w;
    r[4] = (__bf16)b.x; r[5] = (__bf16)b.y; r[6] = (__bf16)b.z; r[7] = (__bf16)b.w;
    return r;
}

// async global->LDS, 16 B per lane; LDS dest = wave-uniform base + lane*16
__device__ __forceinline__ void gload_lds16(const void* g, void* lds) {
    __builtin_amdgcn_global_load_lds(
        (const __attribute__((address_space(1))) void*)g,
        (__attribute__((address_space(3))) void*)lds, 16, 0, 0);
}

// ---- Pass 1: split-K MFMA GEMM, barrier-free 1-wave pipelines, fp32 W ----
// grid = 512 mblocks * 2 kc = 1024 blocks of 64 thr (1 wave) -> EXACTLY 4
// blocks/CU in one residency wave (no scheduling tail), 4 DMA pipelines/CU.
// LDS/buf: A fp32 [16][64] (4 KB) + W fp32 [32][64] (8 KB) = 12 KB; NBUF=3
// -> 36 KB/block. XOR swizzle both sides (rule #21): 16B-unit u ^= (row&7).
// W staged fp32 straight from the gate matrices (r11/r14-verified slabs).
// Spart: [KC][B_ROWS][NJ] (2 MB round trip).
extern "C" __global__ __launch_bounds__(TPB1)
void p1_mfma(const float* __restrict__ x, const float* __restrict__ hx,
             const float* __restrict__ Wf, const float* __restrict__ Wi,
             const float* __restrict__ Wg, const float* __restrict__ Wo,
             float* __restrict__ Spart)
{
    __shared__ float Abuf[NBUF][MROWS * BK];   // 3 x 4 KB
    __shared__ float Bbuf[NBUF][NJ * BK];      // 3 x 8 KB

    const int bid  = blockIdx.x;
    const int kc   = bid & (KC - 1);
    const int mb   = bid >> 1;                  // 0..511
    const int lane = threadIdx.x & 63;
    const int lrow = lane & 15;
    const int rowblk = mb * MROWS;
    const int k0   = kc * CHUNK;                // 0 or 2048

    // kc=0 -> x, kc=1 -> hx; chunk is exactly one matrix, offset 0
    const float* Aglob = (kc == 0)
        ? (x  + (size_t)rowblk * IN_DIM)
        : (hx + (size_t)rowblk * HIDDEN);

    // ---- A staging (pre-swizzled source; r13/r14-verified) ----
    // instr p: row r = p*4 + (l>>4), dest unit l&15, src unit = (l&15)^(r&7)
    int aOff[4];
#pragma unroll
    for (int p = 0; p < 4; ++p) {
        const int r  = p * 4 + (lane >> 4);
        const int cs = (lane & 15) ^ (r & 7);
        aOff[p] = r * 2048 + cs * 4;            // float offset
    }
    // ---- W staging (r11/r14-verified slab addressing) ----
    // slab sl: rows j = sl*4 + (l>>4); gate = j>>3; src off within gate:
    // (j&7)*KDIM + ((l&15)^(j&7))*4 floats
    const float* Wsrc[8] = {Wf, Wf, Wi, Wi, Wg, Wg, Wo, Wo};
    int bOffp[8];
#pragma unroll
    for (int sl = 0; sl < 8; ++sl) {
        const int j  = sl * 4 + (lane >> 4);
        const int j7 = j & 7;
        bOffp[sl] = j7 * KDIM + (((lane & 15) ^ j7) * 4);   // float offset
    }

    // ---- swizzled ds_read_b128 byte offsets (256 B row pitch, fp32) ----
    int offA0[2], offA1[2], offB00[2], offB01[2], offB10[2], offB11[2];
#pragma unroll
    for (int st = 0; st < 2; ++st) {
        const int cu = st * 8 + (lane >> 4) * 2;
        offA0[st]  = lrow * 256 + (((cu + 0) ^ (lane & 7)) * 16);
        offA1[st]  = lrow * 256 + (((cu + 1) ^ (lane & 7)) * 16);
        offB00[st] = lrow * 256        + (((cu + 0) ^ (lane & 7)) * 16);
        offB01[st] = lrow * 256        + (((cu + 1) ^ (lane & 7)) * 16);
        offB10[st] = (lrow + 16) * 256 + (((cu + 0) ^ (lane & 7)) * 16);
        offB11[st] = (lrow + 16) * 256 + (((cu + 1) ^ (lane & 7)) * 16);
    }

    f32x4 acc0 = {0.f, 0.f, 0.f, 0.f};   // j = lrow      (gates f,i)
    f32x4 acc1 = {0.f, 0.f, 0.f, 0.f};   // j = 16 + lrow (gates g,o)

    auto issue = [&](int s) {
        const int b = s % NBUF;
#pragma unroll
        for (int p = 0; p < 4; ++p)
            gload_lds16(Aglob + aOff[p] + s * BK, (char*)&Abuf[b][0] + p * 1024);
#pragma unroll
        for (int sl = 0; sl < 8; ++sl)
            gload_lds16(Wsrc[sl] + bOffp[sl] + k0 + s * BK,
                        (char*)&Bbuf[b][0] + sl * 1024);
    };
    auto compute = [&](int s) {
        const int b = s % NBUF;
        const char* Ab = (const char*)&Abuf[b][0];
        const char* Bb = (const char*)&Bbuf[b][0];
#pragma unroll
        for (int st = 0; st < 2; ++st) {
            f32x4 a0  = *reinterpret_cast<const f32x4*>(Ab + offA0[st]);
            f32x4 a1  = *reinterpret_cast<const f32x4*>(Ab + offA1[st]);
            f32x4 w00 = *reinterpret_cast<const f32x4*>(Bb + offB00[st]);
            f32x4 w01 = *reinterpret_cast<const f32x4*>(Bb + offB01[st]);
            f32x4 w10 = *reinterpret_cast<const f32x4*>(Bb + offB10[st]);
            f32x4 w11 = *reinterpret_cast<const f32x4*>(Bb + offB11[st]);
            bf16x8 af  = cvt8(a0, a1);
            bf16x8 bf0 = cvt8(w00, w01);
            bf16x8 bf1 = cvt8(w10, w11);
            acc0 = __builtin_amdgcn_mfma_f32_16x16x32_bf16(af, bf0, acc0, 0, 0, 0);
            acc1 = __builtin_amdgcn_mfma_f32_16x16x32_bf16(af, bf1, acc1, 0, 0, 0);
        }
    };

    // ---- BARRIER-FREE pipeline: depth-2 prefetch, counted per-wave vmcnt.
    // 12 loads/batch; outstanding after issue(s+2) = {s+1,s+2} = 24
    // -> vmcnt(24) implies batch s landed. Tail: 12, then 0.
    // Buffer safety (single wave, sequential): writer at iter s targets buf
    // (s+2)%3; the only concurrent reader is compute(s) on buf s%3 --
    // distance 2 mod 3 != 0; prior contents of (s+2)%3 were consumed at
    // compute(s-1), which precedes issue(s+2) in program order.
    issue(0);
    issue(1);
#pragma unroll 4
    for (int s = 0; s < SUBT; ++s) {
        if (s + 2 < SUBT) issue(s + 2);
        if (s < SUBT - 2)
            asm volatile("s_waitcnt vmcnt(24)" ::: "memory");
        else if (s == SUBT - 2)
            asm volatile("s_waitcnt vmcnt(12)" ::: "memory");
        else
            asm volatile("s_waitcnt vmcnt(0)" ::: "memory");
        __builtin_amdgcn_sched_barrier(0);      // no ds_read hoist (rule #18)
        compute(s);
    }

    // D layout (16x16x32): col = lane&15, row = (lane>>4)*4 + reg
    float* sp = Spart + ((size_t)kc * B_ROWS + rowblk) * NJ;
    const int m0 = (lane >> 4) * 4;
#pragma unroll
    for (int r = 0; r < 4; ++r) {
        sp[(size_t)(m0 + r) * NJ + lrow]      = acc0[r];
        sp[(size_t)(m0 + r) * NJ + 16 + lrow] = acc1[r];
    }
}

// ------ Pass 2: sum partials, bias, cos, per-block partial -> qpart -------
// grid = 256 blocks * 256 thr; each thread: 4 (row,j) pairs. No atomics.
extern "C" __global__ __launch_bounds__(256)
void p2_cos_reduce(const float* __restrict__ Spart,
                   const float* __restrict__ bf, const float* __restrict__ bi,
                   const float* __restrict__ bg, const float* __restrict__ bo,
                   float* __restrict__ qpart)
{
    __shared__ float ql[4];
    if (threadIdx.x < 4) ql[threadIdx.x] = 0.f;
    __syncthreads();

    const int t    = blockIdx.x * 256 + threadIdx.x;  // 0..65535
    const int j    = t & 31;
    const int gate = j >> 3;
    const float* Bp = (gate == 0) ? bf : (gate == 1) ? bi : (gate == 2) ? bg : bo;
    const float bj = Bp[j & 7];

    float accg = 0.f;
#pragma unroll
    for (int i = 0; i < 4; ++i) {
        const int row = (t >> 5) + i * 2048;
        float s = Spart[((size_t)0 * B_ROWS + row) * NJ + j]
                + Spart[((size_t)1 * B_ROWS + row) * NJ + j];
        accg += cosf(s + bj);
    }

    accg += __shfl_xor(accg, 1, 64);
    accg += __shfl_xor(accg, 2, 64);
    accg += __shfl_xor(accg, 4, 64);
    if ((threadIdx.x & 7) == 0) atomicAdd(&ql[gate], accg);   // LDS only
    __syncthreads();
    if (threadIdx.x < 4) qpart[blockIdx.x * 4 + threadIdx.x] = ql[threadIdx.x];
}

// -------- Pass 3: reduce qpart (4 KB, L2) + elementwise LSTM update -------
// cx: NORMAL load (re-read every replay -> keep L3-resident).
// out: NON-TEMPORAL store (write-once stream -> don't evict inputs from L3).
extern "C" __global__ __launch_bounds__(256)
void p3_elementwise(const float* __restrict__ cx, const float* __restrict__ qpart,
                    float* __restrict__ out)
{
    __shared__ float qs[4][4];                  // [wave][gate]
    const int tid  = threadIdx.x;
    const int wave = tid >> 6;
    const int lane = tid & 63;

    // block-local reduce of qpart[256][4] (one f32x4 per thread)
    f32x4 qp = *reinterpret_cast<const f32x4*>(qpart + tid * 4);
#pragma unroll
    for (int m = 1; m <= 32; m <<= 1) {
        qp.x += __shfl_xor(qp.x, m, 64);
        qp.y += __shfl_xor(qp.y, m, 64);
        qp.z += __shfl_xor(qp.z, m, 64);
        qp.w += __shfl_xor(qp.w, m, 64);
    }
    if (lane == 0) {
        qs[wave][0] = qp.x; qs[wave][1] = qp.y;
        qs[wave][2] = qp.z; qs[wave][3] = qp.w;
    }
    __syncthreads();
    const float qf = qs[0][0] + qs[1][0] + qs[2][0] + qs[3][0];
    const float qi = qs[0][1] + qs[1][1] + qs[2][1] + qs[3][1];
    const float qg = qs[0][2] + qs[1][2] + qs[2][2] + qs[3][2];
    const float qo = qs[0][3] + qs[1][3] + qs[2][3] + qs[3][3];

    const float f  = 1.f / (1.f + expf(-qf));
    const float ii = 1.f / (1.f + expf(-qi));
    const float g  = tanhf(qg);
    const float o  = 1.f / (1.f + expf(-qo));
    const float ig = ii * g;

    const size_t N  = (size_t)B_ROWS * HIDDEN;
    const size_t N4 = N >> 2;
    const f32x4* cx4 = (const f32x4*)cx;
    f32x4* outh = (f32x4*)out;
    f32x4* outc = (f32x4*)(out + N);

    for (size_t idx = (size_t)blockIdx.x * blockDim.x + tid; idx < N4;
         idx += (size_t)gridDim.x * blockDim.x) {
        f32x4 c = cx4[idx];                       // L3-resident across replays
        f32x4 cn, hn;
        cn.x = fmaf(f, c.x, ig);
        cn.y = fmaf(f, c.y, ig);
        cn.z = fmaf(f, c.z, ig);
        cn.w = fmaf(f, c.w, ig);
        hn.x = o * tanhf(cn.x);
        hn.y = o * tanhf(cn.y);
        hn.z = o * tanhf(cn.z);
        hn.w = o * tanhf(cn.w);
        __builtin_nontemporal_store(cn, outc + idx);
        __builtin_nontemporal_store(hn, outh + idx);
    }
}

// ---------------- launcher: THREE dispatches, no atomics, no memset -------
extern "C" void kernel_launch(void* const* d_in, const int* in_sizes, int n_in,
                              void* d_out, int out_size, void* d_ws, size_t ws_size,
                              hipStream_t stream)
{
    const float* x  = (const float*)d_in[0];
    const float* hx = (const float*)d_in[1];
    const float* cx = (const float*)d_in[2];
    const float* Wf = (const float*)d_in[3];
    const float* bf = (const float*)d_in[4];
    const float* Wi = (const float*)d_in[5];
    const float* bi = (const float*)d_in[6];
    const float* Wg = (const float*)d_in[7];
    const float* bg = (const float*)d_in[8];
    const float* Wo = (const float*)d_in[9];
    const float* bo = (const float*)d_in[10];
    float* out = (float*)d_out;

    // ws layout: Spart [KC][8192][32] f32 (2 MB) | qpart [256][4] f32
    float* Spart = (float*)d_ws;
    float* qpart = Spart + (size_t)KC * B_ROWS * NJ;

    p1_mfma<<<dim3(512 * KC), dim3(TPB1), 0, stream>>>(
        x, hx, Wf, Wi, Wg, Wo, Spart);
    p2_cos_reduce<<<dim3(256), dim3(256), 0, stream>>>(
        Spart, bf, bi, bg, bo, qpart);
    p3_elementwise<<<dim3(2048), dim3(256), 0, stream>>>(cx, qpart, out);
}

// Round 18
// 63.632 us; speedup vs baseline: 1.0432x; 1.0432x over previous
//
#include <hip/hip_runtime.h>
#include <hip/hip_bf16.h>
#include <cstdint>
#include <cstddef>

#define B_ROWS 8192
#define KDIM   4096
#define IN_DIM 2048
#define HIDDEN 2048
#define NJ     32           // 4 gates x 8 wires
#define KC     4            // K-split across blocks
#define CHUNK  (KDIM / KC)  // 1024
#define BK     64           // k-subtile per pipeline stage
#define SUBT   (CHUNK / BK) // 16
#define MROWS  16           // rows per block (ONE wave)
#define TPB1   64           // 1 wave -> no s_barrier anywhere in the K-loop
#define NBUF   3            // depth-2 prefetch (single-wave: distance-2 mod 3 safe)

typedef __bf16 bf16x8 __attribute__((ext_vector_type(8)));
typedef float  f32x4  __attribute__((ext_vector_type(4)));

__device__ __forceinline__ bf16x8 cvt8(f32x4 a, f32x4 b) {
    bf16x8 r;
    r[0] = (__bf16)a.x; r[1] = (__bf16)a.y; r[2] = (__bf16)a.z; r[3] = (__bf16)a.w;
    r[4] = (__bf16)b.x; r[5] = (__bf16)b.y; r[6] = (__bf16)b.z; r[7] = (__bf16)b.w;
    return r;
}

// async global->LDS, 16 B per lane; LDS dest = wave-uniform base + lane*16
__device__ __forceinline__ void gload_lds16(const void* g, void* lds) {
    __builtin_amdgcn_global_load_lds(
        (const __attribute__((address_space(1))) void*)g,
        (__attribute__((address_space(3))) void*)lds, 16, 0, 0);
}

// ---- Pass 1: split-K MFMA GEMM, barrier-free 1-wave pipelines, fp32 W ----
// grid = 2048 blocks of 64 thr (1 wave); mapping mb = bid & 511 (FASTEST),
// kc = bid >> 9 -> consecutive blocks share the W chunk and read adjacent
// A row-tiles (DRAM page + L2 locality). 2048 fine blocks = 8 slots/CU ->
// inter-block overlap hides per-block pipeline fill (r14 vs r17 lesson).
// LDS/buf: A fp32 [16][64] (4 KB) + W fp32 [32][64] (8 KB) = 12 KB; NBUF=3
// -> 36 KB/block -> 4 blocks/CU resident. XOR swizzle both sides (rule #21):
// 16B-unit u ^= (row & 7). W staged fp32 direct (r11/r14-verified slabs).
// Spart layout: [KC][B_ROWS][NJ]
extern "C" __global__ __launch_bounds__(TPB1)
void p1_mfma(const float* __restrict__ x, const float* __restrict__ hx,
             const float* __restrict__ Wf, const float* __restrict__ Wi,
             const float* __restrict__ Wg, const float* __restrict__ Wo,
             float* __restrict__ Spart)
{
    __shared__ float Abuf[NBUF][MROWS * BK];   // 3 x 4 KB
    __shared__ float Bbuf[NBUF][NJ * BK];      // 3 x 8 KB

    const int bid  = blockIdx.x;
    const int mb   = bid & 511;                 // FASTEST: adjacent rows
    const int kc   = bid >> 9;                  // 0..3
    const int lane = threadIdx.x & 63;
    const int lrow = lane & 15;
    const int rowblk = mb * MROWS;
    const int k0   = kc * CHUNK;

    // x / hx share row stride 2048; a 1024-chunk never straddles them
    const float* Aglob = (kc < 2)
        ? (x  + (size_t)rowblk * IN_DIM + k0)
        : (hx + (size_t)rowblk * HIDDEN + (k0 - IN_DIM));

    // ---- A staging (pre-swizzled source; r13/r14-verified) ----
    // instr p: row r = p*4 + (l>>4), dest unit l&15, src unit = (l&15)^(r&7)
    int aOff[4];
#pragma unroll
    for (int p = 0; p < 4; ++p) {
        const int r  = p * 4 + (lane >> 4);
        const int cs = (lane & 15) ^ (r & 7);
        aOff[p] = r * 2048 + cs * 4;            // float offset
    }
    // ---- W staging (r11/r14-verified slab addressing) ----
    // slab sl: rows j = sl*4 + (l>>4); gate = j>>3; src off within gate:
    // (j&7)*KDIM + ((l&15)^(j&7))*4 floats
    const float* Wsrc[8] = {Wf, Wf, Wi, Wi, Wg, Wg, Wo, Wo};
    int bOffp[8];
#pragma unroll
    for (int sl = 0; sl < 8; ++sl) {
        const int j  = sl * 4 + (lane >> 4);
        const int j7 = j & 7;
        bOffp[sl] = j7 * KDIM + (((lane & 15) ^ j7) * 4);   // float offset
    }

    // ---- swizzled ds_read_b128 byte offsets (256 B row pitch, fp32) ----
    int offA0[2], offA1[2], offB00[2], offB01[2], offB10[2], offB11[2];
#pragma unroll
    for (int st = 0; st < 2; ++st) {
        const int cu = st * 8 + (lane >> 4) * 2;
        offA0[st]  = lrow * 256 + (((cu + 0) ^ (lane & 7)) * 16);
        offA1[st]  = lrow * 256 + (((cu + 1) ^ (lane & 7)) * 16);
        offB00[st] = lrow * 256        + (((cu + 0) ^ (lane & 7)) * 16);
        offB01[st] = lrow * 256        + (((cu + 1) ^ (lane & 7)) * 16);
        offB10[st] = (lrow + 16) * 256 + (((cu + 0) ^ (lane & 7)) * 16);
        offB11[st] = (lrow + 16) * 256 + (((cu + 1) ^ (lane & 7)) * 16);
    }

    f32x4 acc0 = {0.f, 0.f, 0.f, 0.f};   // j = lrow      (gates f,i)
    f32x4 acc1 = {0.f, 0.f, 0.f, 0.f};   // j = 16 + lrow (gates g,o)

    auto issue = [&](int s) {
        const int b = s % NBUF;
#pragma unroll
        for (int p = 0; p < 4; ++p)
            gload_lds16(Aglob + aOff[p] + s * BK, (char*)&Abuf[b][0] + p * 1024);
#pragma unroll
        for (int sl = 0; sl < 8; ++sl)
            gload_lds16(Wsrc[sl] + bOffp[sl] + k0 + s * BK,
                        (char*)&Bbuf[b][0] + sl * 1024);
    };
    auto compute = [&](int s) {
        const int b = s % NBUF;
        const char* Ab = (const char*)&Abuf[b][0];
        const char* Bb = (const char*)&Bbuf[b][0];
#pragma unroll
        for (int st = 0; st < 2; ++st) {
            f32x4 a0  = *reinterpret_cast<const f32x4*>(Ab + offA0[st]);
            f32x4 a1  = *reinterpret_cast<const f32x4*>(Ab + offA1[st]);
            f32x4 w00 = *reinterpret_cast<const f32x4*>(Bb + offB00[st]);
            f32x4 w01 = *reinterpret_cast<const f32x4*>(Bb + offB01[st]);
            f32x4 w10 = *reinterpret_cast<const f32x4*>(Bb + offB10[st]);
            f32x4 w11 = *reinterpret_cast<const f32x4*>(Bb + offB11[st]);
            bf16x8 af  = cvt8(a0, a1);
            bf16x8 bf0 = cvt8(w00, w01);
            bf16x8 bf1 = cvt8(w10, w11);
            acc0 = __builtin_amdgcn_mfma_f32_16x16x32_bf16(af, bf0, acc0, 0, 0, 0);
            acc1 = __builtin_amdgcn_mfma_f32_16x16x32_bf16(af, bf1, acc1, 0, 0, 0);
        }
    };

    // ---- BARRIER-FREE pipeline: depth-2 prefetch, counted per-wave vmcnt.
    // 12 loads/batch; outstanding after issue(s+2) = {s+1,s+2} = 24
    // -> vmcnt(24) implies batch s landed. Tail: 12, then 0.
    // Buffer safety (single wave, sequential): writer at iter s targets buf
    // (s+2)%3; the only concurrent reader is compute(s) on buf s%3 --
    // distance 2 mod 3 != 0; prior contents of (s+2)%3 were consumed at
    // compute(s-1), which precedes issue(s+2) in program order.
    issue(0);
    issue(1);
#pragma unroll
    for (int s = 0; s < SUBT; ++s) {
        if (s + 2 < SUBT) issue(s + 2);
        if (s < SUBT - 2)
            asm volatile("s_waitcnt vmcnt(24)" ::: "memory");
        else if (s == SUBT - 2)
            asm volatile("s_waitcnt vmcnt(12)" ::: "memory");
        else
            asm volatile("s_waitcnt vmcnt(0)" ::: "memory");
        __builtin_amdgcn_sched_barrier(0);      // no ds_read hoist (rule #18)
        compute(s);
    }

    // D layout (16x16x32): col = lane&15, row = (lane>>4)*4 + reg
    float* sp = Spart + ((size_t)kc * B_ROWS + rowblk) * NJ;
    const int m0 = (lane >> 4) * 4;
#pragma unroll
    for (int r = 0; r < 4; ++r) {
        sp[(size_t)(m0 + r) * NJ + lrow]      = acc0[r];
        sp[(size_t)(m0 + r) * NJ + 16 + lrow] = acc1[r];
    }
}

// ------ Pass 2: sum partials, bias, cos, per-block partial -> qpart -------
// grid = 256 blocks * 256 thr; each thread: 4 (row,j) pairs. No atomics.
extern "C" __global__ __launch_bounds__(256)
void p2_cos_reduce(const float* __restrict__ Spart,
                   const float* __restrict__ bf, const float* __restrict__ bi,
                   const float* __restrict__ bg, const float* __restrict__ bo,
                   float* __restrict__ qpart)
{
    __shared__ float ql[4];
    if (threadIdx.x < 4) ql[threadIdx.x] = 0.f;
    __syncthreads();

    const int t    = blockIdx.x * 256 + threadIdx.x;  // 0..65535
    const int j    = t & 31;
    const int gate = j >> 3;
    const float* Bp = (gate == 0) ? bf : (gate == 1) ? bi : (gate == 2) ? bg : bo;
    const float bj = Bp[j & 7];

    float accg = 0.f;
#pragma unroll
    for (int i = 0; i < 4; ++i) {
        const int row = (t >> 5) + i * 2048;
        float s = 0.f;
#pragma unroll
        for (int kc = 0; kc < KC; ++kc)
            s += Spart[((size_t)kc * B_ROWS + row) * NJ + j];
        accg += cosf(s + bj);
    }

    accg += __shfl_xor(accg, 1, 64);
    accg += __shfl_xor(accg, 2, 64);
    accg += __shfl_xor(accg, 4, 64);
    if ((threadIdx.x & 7) == 0) atomicAdd(&ql[gate], accg);   // LDS only
    __syncthreads();
    if (threadIdx.x < 4) qpart[blockIdx.x * 4 + threadIdx.x] = ql[threadIdx.x];
}

// -------- Pass 3: reduce qpart (4 KB, L2) + elementwise LSTM update -------
// cx: NORMAL load (re-read every replay -> keep L3-resident).
// out: NON-TEMPORAL store (write-once stream -> don't evict inputs from L3).
// Compile-time 8 iterations/thread (2048 blocks x 256 thr): full unroll,
// all 8 independent loads issued early for MLP.
extern "C" __global__ __launch_bounds__(256)
void p3_elementwise(const float* __restrict__ cx, const float* __restrict__ qpart,
                    float* __restrict__ out)
{
    __shared__ float qs[4][4];                  // [wave][gate]
    const int tid  = threadIdx.x;
    const int wave = tid >> 6;
    const int lane = tid & 63;

    // block-local reduce of qpart[256][4] (one f32x4 per thread)
    f32x4 qp = *reinterpret_cast<const f32x4*>(qpart + tid * 4);
#pragma unroll
    for (int m = 1; m <= 32; m <<= 1) {
        qp.x += __shfl_xor(qp.x, m, 64);
        qp.y += __shfl_xor(qp.y, m, 64);
        qp.z += __shfl_xor(qp.z, m, 64);
        qp.w += __shfl_xor(qp.w, m, 64);
    }
    if (lane == 0) {
        qs[wave][0] = qp.x; qs[wave][1] = qp.y;
        qs[wave][2] = qp.z; qs[wave][3] = qp.w;
    }
    __syncthreads();
    const float qf = qs[0][0] + qs[1][0] + qs[2][0] + qs[3][0];
    const float qi = qs[0][1] + qs[1][1] + qs[2][1] + qs[3][1];
    const float qg = qs[0][2] + qs[1][2] + qs[2][2] + qs[3][2];
    const float qo = qs[0][3] + qs[1][3] + qs[2][3] + qs[3][3];

    const float f  = 1.f / (1.f + expf(-qf));
    const float ii = 1.f / (1.f + expf(-qi));
    const float g  = tanhf(qg);
    const float o  = 1.f / (1.f + expf(-qo));
    const float ig = ii * g;

    const size_t N  = (size_t)B_ROWS * HIDDEN;     // 16,777,216
    const int    gt = blockIdx.x * 256 + tid;      // 0..524287
    const f32x4* cx4 = (const f32x4*)cx;
    f32x4* outh = (f32x4*)out;
    f32x4* outc = (f32x4*)(out + N);

#pragma unroll
    for (int it = 0; it < 8; ++it) {               // 8 x 524288 = N/4
        const size_t idx = (size_t)it * 524288 + gt;
        f32x4 c = cx4[idx];                        // L3-resident across replays
        f32x4 cn, hn;
        cn.x = fmaf(f, c.x, ig);
        cn.y = fmaf(f, c.y, ig);
        cn.z = fmaf(f, c.z, ig);
        cn.w = fmaf(f, c.w, ig);
        hn.x = o * tanhf(cn.x);
        hn.y = o * tanhf(cn.y);
        hn.z = o * tanhf(cn.z);
        hn.w = o * tanhf(cn.w);
        __builtin_nontemporal_store(cn, outc + idx);
        __builtin_nontemporal_store(hn, outh + idx);
    }
}

// ---------------- launcher: THREE dispatches, no atomics, no memset -------
extern "C" void kernel_launch(void* const* d_in, const int* in_sizes, int n_in,
                              void* d_out, int out_size, void* d_ws, size_t ws_size,
                              hipStream_t stream)
{
    const float* x  = (const float*)d_in[0];
    const float* hx = (const float*)d_in[1];
    const float* cx = (const float*)d_in[2];
    const float* Wf = (const float*)d_in[3];
    const float* bf = (const float*)d_in[4];
    const float* Wi = (const float*)d_in[5];
    const float* bi = (const float*)d_in[6];
    const float* Wg = (const float*)d_in[7];
    const float* bg = (const float*)d_in[8];
    const float* Wo = (const float*)d_in[9];
    const float* bo = (const float*)d_in[10];
    float* out = (float*)d_out;

    // ws layout: Spart [KC][8192][32] f32 (4 MB) | qpart [256][4] f32
    float* Spart = (float*)d_ws;
    float* qpart = Spart + (size_t)KC * B_ROWS * NJ;

    p1_mfma<<<dim3(512 * KC), dim3(TPB1), 0, stream>>>(
        x, hx, Wf, Wi, Wg, Wo, Spart);
    p2_cos_reduce<<<dim3(256), dim3(256), 0, stream>>>(
        Spart, bf, bi, bg, bo, qpart);
    p3_elementwise<<<dim3(2048), dim3(256), 0, stream>>>(cx, qpart, out);
}